// Round 14
// baseline (15670.851 us; speedup 1.0000x reference)
//
#include <hip/hip_runtime.h>
#include <math.h>

// ---- problem constants ----
#define NB   64      // batch
#define TT   150     // timesteps
#define CIN  150
#define HH   1024
#define G3   3072    // 3*H
#define NCOL 6144    // 2*3072 (both directions)
#define KP0  160     // CIN padded to mult of 32
#define RT   9600    // T*N rows
#define NC   60
#define NSLOT 151            // h slots per direction (slot 0 = zeros)
#define SLOT_STRIDE 66560    // 64*1024 elems + 2048 elem (4KB) pad

using bf16x8 = __attribute__((ext_vector_type(8))) __bf16;
using f32x4  = __attribute__((ext_vector_type(4))) float;

static __device__ __forceinline__ unsigned short f2bf(float f){
  unsigned int x = __builtin_bit_cast(unsigned int, f);
  x += 0x7fffu + ((x >> 16) & 1u);          // RNE
  return (unsigned short)(x >> 16);
}
static __device__ __forceinline__ float bf2f(unsigned short u){
  unsigned int x = ((unsigned int)u) << 16;
  return __builtin_bit_cast(float, x);
}
static __device__ __forceinline__ float sigmoidf(float x){
  return 1.0f / (1.0f + expf(-x));
}

// async global->LDS, 16B per lane; LDS dest = wave-uniform base + lane*16
static __device__ __forceinline__ void gload16(const void* g, void* l){
  __builtin_amdgcn_global_load_lds(
      (const __attribute__((address_space(1))) void*)g,
      (__attribute__((address_space(3))) void*)l, 16, 0, 0);
}

// ---- BatchNorm stats: one block per channel ----
__global__ void bn_stats(const float* __restrict__ x, const float* __restrict__ gamma,
                         const float* __restrict__ beta, float* __restrict__ ss){
  const int c = blockIdx.x;
  float s = 0.f, s2 = 0.f;
  for (int i = threadIdx.x; i < RT; i += 256){
    float v = x[(size_t)i * CIN + c];
    s += v; s2 += v * v;
  }
  __shared__ float sh1[256], sh2[256];
  sh1[threadIdx.x] = s; sh2[threadIdx.x] = s2;
  __syncthreads();
  for (int st = 128; st > 0; st >>= 1){
    if ((int)threadIdx.x < st){
      sh1[threadIdx.x] += sh1[threadIdx.x + st];
      sh2[threadIdx.x] += sh2[threadIdx.x + st];
    }
    __syncthreads();
  }
  if (threadIdx.x == 0){
    float mean = sh1[0] * (1.f / RT);
    float var  = sh2[0] * (1.f / RT) - mean * mean;
    float sc   = rsqrtf(var + 1e-5f) * gamma[c];
    ss[c]       = sc;
    ss[CIN + c] = beta[c] - mean * sc;
  }
}

// ---- normalize + transpose [N,T,C] -> bf16 [t*64+n, KP0] with zero pad ----
__global__ void bn_apply(const float* __restrict__ x, const float* __restrict__ ss,
                         unsigned short* __restrict__ xn){
  int idx = blockIdx.x * 256 + threadIdx.x;
  if (idx >= RT * KP0) return;
  int r = idx / KP0, c = idx - r * KP0;
  int t = r >> 6, n = r & 63;
  float v = 0.f;
  if (c < CIN) v = x[((size_t)n * TT + t) * CIN + c] * ss[c] + ss[CIN + c];
  xn[idx] = f2bf(v);
}

// ---- cast fp32 -> bf16 (grid stride) ----
__global__ void cast_bf(const float* __restrict__ s, unsigned short* __restrict__ d, int n){
  for (int i = blockIdx.x * 256 + threadIdx.x; i < n; i += gridDim.x * 256)
    d[i] = f2bf(s[i]);
}

// ---- cast + pad w_ih0 [6144,150] -> [6144,160] bf16 ----
__global__ void cast_pad_w0(const float* __restrict__ w, unsigned short* __restrict__ d){
  int idx = blockIdx.x * 256 + threadIdx.x;
  if (idx >= NCOL * KP0) return;
  int row = idx / KP0, c = idx - row * KP0;
  d[idx] = (c < CIN) ? f2bf(w[(size_t)row * CIN + c]) : (unsigned short)0;
}

__global__ void zero16(uint4* p, int n){
  int i = blockIdx.x * 256 + threadIdx.x;
  if (i < n) p[i] = make_uint4(0u, 0u, 0u, 0u);
}

__global__ void guard_k(float* out){ out[0] = -12345.0f; }

// ---- tiled gi GEMM (layer 0 only): C[r,col] = sum_k A[r,k]*B[col,k] + bias[col]
__global__ __launch_bounds__(256) void gemm_tile(
    const unsigned short* __restrict__ A, const unsigned short* __restrict__ B,
    const float* __restrict__ bias, unsigned short* __restrict__ C, int K)
{
  const int r0 = blockIdx.x * 128;
  const int c0 = blockIdx.y * 128;
  const int tid = threadIdx.x;
  const int wid = tid >> 6;
  const int l   = tid & 63;
  const int lr  = l & 15;
  const int lk  = (l >> 4) * 8;
  const int wm  = wid >> 1;       // wave row quadrant
  const int wn  = wid & 1;        // wave col quadrant

  __shared__ unsigned short As[128 * 32];
  __shared__ unsigned short Bs[128 * 32];

  const int c1   = wid * 64 + l;      // 16B-chunk id 0..255
  const int rowS = c1 >> 2;           // 0..63
  const int ccS  = c1 & 3;            // 16B chunk within row

  f32x4 acc[4][4];
#pragma unroll
  for (int i = 0; i < 4; ++i)
#pragma unroll
    for (int j = 0; j < 4; ++j) acc[i][j] = f32x4{0,0,0,0};

  const unsigned short* Ag0 = A + (size_t)(r0 + rowS) * K + ccS * 8;
  const unsigned short* Ag1 = A + (size_t)(r0 + 64 + rowS) * K + ccS * 8;
  const unsigned short* Bg0 = B + (size_t)(c0 + rowS) * K + ccS * 8;
  const unsigned short* Bg1 = B + (size_t)(c0 + 64 + rowS) * K + ccS * 8;
  unsigned short* As0 = As + wid * 512;
  unsigned short* As1 = As + 2048 + wid * 512;
  unsigned short* Bs0 = Bs + wid * 512;
  unsigned short* Bs1 = Bs + 2048 + wid * 512;

  for (int k0 = 0; k0 < K; k0 += 32){
    gload16(Ag0 + k0, As0);
    gload16(Ag1 + k0, As1);
    gload16(Bg0 + k0, Bs0);
    gload16(Bg1 + k0, Bs1);
    __syncthreads();

    bf16x8 af[4], bfr[4];
#pragma unroll
    for (int mt = 0; mt < 4; ++mt)
      af[mt] = *(const bf16x8*)(As + (wm * 64 + mt * 16 + lr) * 32 + lk);
#pragma unroll
    for (int nt = 0; nt < 4; ++nt)
      bfr[nt] = *(const bf16x8*)(Bs + (wn * 64 + nt * 16 + lr) * 32 + lk);
#pragma unroll
    for (int mt = 0; mt < 4; ++mt)
#pragma unroll
      for (int nt = 0; nt < 4; ++nt)
        acc[mt][nt] = __builtin_amdgcn_mfma_f32_16x16x32_bf16(af[mt], bfr[nt], acc[mt][nt], 0, 0, 0);
    __syncthreads();
  }

  const int rb = (l >> 4) * 4;
#pragma unroll
  for (int mt = 0; mt < 4; ++mt){
#pragma unroll
    for (int nt = 0; nt < 4; ++nt){
      const int col = c0 + wn * 64 + nt * 16 + lr;
      const float bv = bias[col];
#pragma unroll
      for (int reg = 0; reg < 4; ++reg){
        const int row = r0 + wm * 64 + mt * 16 + rb + reg;
        C[(size_t)row * NCOL + col] = f2bf(acc[mt][nt][reg] + bv);
      }
    }
  }
}

// ============== fused persistent layer: GRU (blocks 0-127) + gi-GEMM workers
// (blocks 128-255, next layer's input projection, stripe-gated on counters) ====
// GRU part identical to r13 (16 waves, weights in LDS, write-once h slots,
// single counter/dir) except outb stores are 8B agent write-through atomics.
// Workers: stripe t of gi_next[t*64.., col range] = out[t stripe] @ wih_next^T
// + bias, gated on BOTH dir counters >= 64*(t+1) (orders against all gru reads
// of gi[t]/outb[t] -> in-place gi overwrite is race-free).
__global__ __launch_bounds__(1024, 1) void fused_layer(
    const unsigned short* __restrict__ whh,   // [2][3072][1024] bf16
    const float* __restrict__ bhh,            // [2][3072]
    unsigned short* __restrict__ gi,          // [9600][6144] bf16 (read l, write l+1)
    unsigned short* __restrict__ outb,        // [9600][2048] bf16
    float* __restrict__ hfinal,               // [2][64][1024] f32 (t=149)
    unsigned short* __restrict__ hbig,        // [2][NSLOT][SLOT_STRIDE] bf16
    int* __restrict__ flags, int wout,
    const unsigned short* __restrict__ wih_next,  // [6144][2048] bf16
    const float* __restrict__ bih_next,           // [6144]
    int do_next)
{
  __shared__ unsigned char wlds[98304];   // 3 planes of 32KB
  __shared__ f32x4 red4[2304];            // [12 src waves][3 gates][64 lanes]

  const int tid = threadIdx.x;
  const int w  = tid >> 6;
  const int l  = tid & 63;
  const int lr = l & 15;
  const int hi = l >> 4;

  if (blockIdx.x >= 128){
    // ================= GEMM worker role =================
    if (!do_next) return;
    if (w >= 12) return;                  // 12 active waves
    const int wk = blockIdx.x - 128;      // 0..127 -> 48-col slice
    const int rt = w >> 2;                // wait: need 4 rowtiles x 3 coltiles
    // w in [0,12): rowtile = w / 3, coltile = w % 3
    const int rtile = w / 3;
    const int ctile = w - rtile * 3;
    const int c0 = wk * 48 + ctile * 16;
    const int lk = hi * 8;
    (void)rt;
    const float bv = bih_next[c0 + lr];
    int* ctr0 = &flags[0];
    int* ctr1 = &flags[64];
    const int rb = hi * 4;

    for (int t = 0; t < TT; ++t){
      const int tgt = 64 * (t + 1);
      int cap = 0;
      while (__hip_atomic_load(ctr0, __ATOMIC_RELAXED, __HIP_MEMORY_SCOPE_AGENT) < tgt ||
             __hip_atomic_load(ctr1, __ATOMIC_RELAXED, __HIP_MEMORY_SCOPE_AGENT) < tgt){
        if (++cap > 50000000) break;
        __builtin_amdgcn_s_sleep(2);
      }
      const unsigned short* Arow = outb + (size_t)(t * 64 + rtile * 16 + lr) * (2 * HH) + lk;
      const unsigned short* Brow = wih_next + (size_t)(c0 + lr) * (2 * HH) + lk;
      f32x4 acc = {0, 0, 0, 0};
      for (int k0 = 0; k0 < 2 * HH; k0 += 32){
        bf16x8 a = *(const bf16x8*)(Arow + k0);
        bf16x8 b = *(const bf16x8*)(Brow + k0);
        acc = __builtin_amdgcn_mfma_f32_16x16x32_bf16(a, b, acc, 0, 0, 0);
      }
#pragma unroll
      for (int reg = 0; reg < 4; ++reg){
        const int row = t * 64 + rtile * 16 + rb + reg;
        gi[(size_t)row * NCOL + c0 + lr] = f2bf(acc[reg] + bv);
      }
    }
    return;
  }

  // ================= GRU role (identical to r13) =================
  const int d  = blockIdx.x >> 6;
  const int jt = blockIdx.x & 63;
  const int j0 = jt * 16;
  const int wq = w & 3;           // row quad (16 batch rows)
  const int kq = w >> 2;          // k quarter

  {
    const unsigned short* wsrc = whh + (size_t)d * (G3 * HH);
    for (int c = tid; c < 6144; c += 1024){    // 16B chunks
      int g   = c >> 11;
      int rem = c & 2047;
      int r   = rem >> 7;
      int kc  = rem & 127;
      uint4 v = *(const uint4*)(wsrc + (size_t)(g * HH + j0 + r) * HH + kc * 8);
      int kcs = (kc & ~7) | ((kc + r) & 7);
      *(uint4*)(wlds + g * 32768 + r * 2048 + kcs * 16) = v;
    }
  }
  __syncthreads();

  float4 br4 = make_float4(0, 0, 0, 0), bz4 = br4, bn4 = br4;
  if (kq == 0){
    br4 = *(const float4*)(bhh + d * G3 +          j0 + hi * 4);
    bz4 = *(const float4*)(bhh + d * G3 + HH +     j0 + hi * 4);
    bn4 = *(const float4*)(bhh + d * G3 + 2 * HH + j0 + hi * 4);
  }

  const int n    = wq * 16 + lr;
  const int jcol = j0 + hi * 4;

  unsigned short* dirbase = hbig + (size_t)d * NSLOT * SLOT_STRIDE;
  int* ctr = &flags[d * 64];

  float hold[4] = {0.f, 0.f, 0.f, 0.f};

  for (int t = 0; t < TT; ++t){
    const unsigned short* hprev = dirbase + (size_t)t * SLOT_STRIDE;
    unsigned short*       hnext = dirbase + (size_t)(t + 1) * SLOT_STRIDE;

    ushort4 gr4, gz4, gn4;
    if (kq == 0){
      size_t gbase = (size_t)(t * NB + n) * NCOL + (size_t)d * G3 + jcol;
      gr4 = *(const ushort4*)(gi + gbase);
      gz4 = *(const ushort4*)(gi + gbase + HH);
      gn4 = *(const ushort4*)(gi + gbase + 2 * HH);
    }

    if (t){
      if (tid == 0){
        const int tgt = 64 * t;
        int cap = 0;
        while (__hip_atomic_load(ctr, __ATOMIC_RELAXED, __HIP_MEMORY_SCOPE_AGENT) < tgt){
          if (++cap > 20000000) break;
          __builtin_amdgcn_s_sleep(1);
        }
      }
      __syncthreads();
    }

    f32x4 ar = {0,0,0,0}, az = {0,0,0,0}, an = {0,0,0,0};
    const unsigned short* hrow = hprev + (size_t)n * HH + kq * 256 + hi * 8;

    bf16x8 ha[8];
#pragma unroll
    for (int i = 0; i < 8; ++i) ha[i] = *(const bf16x8*)(hrow + i * 32);

#pragma unroll
    for (int i = 0; i < 8; ++i){
      const int kc  = kq * 32 + i * 4 + hi;
      const int kcs = (kc & ~7) | ((kc + lr) & 7);
      const int off = lr * 2048 + kcs * 16;
      bf16x8 a_r = *(const bf16x8*)(wlds +          off);
      bf16x8 a_z = *(const bf16x8*)(wlds + 32768 +  off);
      bf16x8 a_n = *(const bf16x8*)(wlds + 65536 +  off);
      ar = __builtin_amdgcn_mfma_f32_16x16x32_bf16(a_r, ha[i], ar, 0, 0, 0);
      az = __builtin_amdgcn_mfma_f32_16x16x32_bf16(a_z, ha[i], az, 0, 0, 0);
      an = __builtin_amdgcn_mfma_f32_16x16x32_bf16(a_n, ha[i], an, 0, 0, 0);
    }

    __syncthreads();
    if (kq > 0){
      const int src = (kq - 1) * 4 + wq;
      red4[(src * 3 + 0) * 64 + l] = ar;
      red4[(src * 3 + 1) * 64 + l] = az;
      red4[(src * 3 + 2) * 64 + l] = an;
    }
    __syncthreads();

    if (kq == 0){
#pragma unroll
      for (int kqp = 1; kqp < 4; ++kqp){
        const int src = (kqp - 1) * 4 + wq;
        ar += red4[(src * 3 + 0) * 64 + l];
        az += red4[(src * 3 + 1) * 64 + l];
        an += red4[(src * 3 + 2) * 64 + l];
      }

      ushort4 hb_;
      const float* br = (const float*)&br4;
      const float* bz = (const float*)&bz4;
      const float* bn_ = (const float*)&bn4;
      const unsigned short* g_r = (const unsigned short*)&gr4;
      const unsigned short* g_z = (const unsigned short*)&gz4;
      const unsigned short* g_n = (const unsigned short*)&gn4;
#pragma unroll
      for (int reg = 0; reg < 4; ++reg){
        float r  = sigmoidf(bf2f(g_r[reg]) + ar[reg] + br[reg]);
        float z  = sigmoidf(bf2f(g_z[reg]) + az[reg] + bz[reg]);
        float nn = tanhf(bf2f(g_n[reg]) + r * (an[reg] + bn_[reg]));
        hold[reg] = (1.f - z) * nn + z * hold[reg];
      }
      hb_.x = f2bf(hold[0]); hb_.y = f2bf(hold[1]);
      hb_.z = f2bf(hold[2]); hb_.w = f2bf(hold[3]);
      __hip_atomic_store((unsigned long long*)(hnext + (size_t)n * HH + jcol),
                         __builtin_bit_cast(unsigned long long, hb_),
                         __ATOMIC_RELAXED, __HIP_MEMORY_SCOPE_AGENT);
      if (wout)
        __hip_atomic_store((unsigned long long*)(outb + (size_t)(t * NB + n) * (2 * HH)
                                                 + (size_t)d * HH + jcol),
                           __builtin_bit_cast(unsigned long long, hb_),
                           __ATOMIC_RELAXED, __HIP_MEMORY_SCOPE_AGENT);
      if (t == TT - 1)
        *(float4*)(hfinal + (size_t)(d * NB + n) * HH + jcol) =
            make_float4(hold[0], hold[1], hold[2], hold[3]);
    }

    __syncthreads();
    if (tid == 0)
      __hip_atomic_fetch_add(ctr, 1, __ATOMIC_RELEASE, __HIP_MEMORY_SCOPE_AGENT);
  }
}

// ---- final FC ----
__global__ void fc_kernel(const float* __restrict__ hf, const float* __restrict__ fw,
                          const float* __restrict__ fb, float* __restrict__ out){
  int b = blockIdx.x;
  int n = b / NC, c = b - n * NC;
  int l = threadIdx.x;
  float s = 0.f;
  for (int k = l; k < 2 * HH; k += 64){
    float hv = (k < HH) ? hf[(size_t)n * HH + k]
                        : hf[(size_t)(NB + n) * HH + (k - HH)];
    s += hv * fw[(size_t)c * (2 * HH) + k];
  }
#pragma unroll
  for (int off = 32; off > 0; off >>= 1) s += __shfl_down(s, off);
  if (l == 0) out[n * NC + c] = s + fb[c];
}

extern "C" void kernel_launch(void* const* d_in, const int* in_sizes, int n_in,
                              void* d_out, int out_size, void* d_ws, size_t ws_size,
                              hipStream_t stream)
{
  const float* x      = (const float*)d_in[0];
  const float* gamma  = (const float*)d_in[1];
  const float* beta   = (const float*)d_in[2];
  const float* w_ih0  = (const float*)d_in[3];
  const float* w_hh0  = (const float*)d_in[4];
  const float* b_ih0  = (const float*)d_in[5];
  const float* b_hh0  = (const float*)d_in[6];
  const float* w_ih   = (const float*)d_in[7];
  const float* w_hh   = (const float*)d_in[8];
  const float* b_ih   = (const float*)d_in[9];
  const float* b_hh   = (const float*)d_in[10];
  const float* fc_w   = (const float*)d_in[11];
  const float* fc_b   = (const float*)d_in[12];
  float* out = (float*)d_out;

  char* ws = (char*)d_ws;
  size_t off = 0;
  auto alloc = [&](size_t bytes)->void*{
    void* p = ws + off; off += (bytes + 255) & ~(size_t)255; return p;
  };
  unsigned short* whh_bf = (unsigned short*)alloc((size_t)3 * 2 * G3 * HH * 2);
  unsigned short* w0_bf  = (unsigned short*)alloc((size_t)NCOL * KP0 * 2);
  unsigned short* wih_bf = (unsigned short*)alloc((size_t)2 * NCOL * 2 * HH * 2);
  unsigned short* xn_bf  = (unsigned short*)alloc((size_t)RT * KP0 * 2);
  unsigned short* gi_bf  = (unsigned short*)alloc((size_t)RT * NCOL * 2);
  unsigned short* out0   = (unsigned short*)alloc((size_t)RT * 2 * HH * 2);
  unsigned short* out1   = (unsigned short*)alloc((size_t)RT * 2 * HH * 2);
  float* hfinal = (float*)alloc((size_t)2 * NB * HH * 4);
  unsigned short* hbig = (unsigned short*)alloc((size_t)2 * NSLOT * SLOT_STRIDE * 2);
  float* ss = (float*)alloc(2048);
  int* flags = (int*)alloc(1024);

  if (off > ws_size){ guard_k<<<1, 1, 0, stream>>>(out); return; }

  // BN + casts
  bn_stats<<<CIN, 256, 0, stream>>>(x, gamma, beta, ss);
  bn_apply<<<(RT * KP0 + 255) / 256, 256, 0, stream>>>(x, ss, xn_bf);
  cast_pad_w0<<<(NCOL * KP0 + 255) / 256, 256, 0, stream>>>(w_ih0, w0_bf);
  cast_bf<<<4096, 256, 0, stream>>>(w_hh0, whh_bf, 2 * G3 * HH);
  cast_bf<<<4096, 256, 0, stream>>>(w_hh,  whh_bf + (size_t)2 * G3 * HH, 2 * 2 * G3 * HH);
  cast_bf<<<4096, 256, 0, stream>>>(w_ih,  wih_bf, 2 * NCOL * 2 * HH);

  // zero slot 0 of both directions (h^0 = 0) — every call (ws is poisoned)
  zero16<<<32, 256, 0, stream>>>((uint4*)hbig, NB * HH * 2 / 16);
  zero16<<<32, 256, 0, stream>>>((uint4*)(hbig + (size_t)NSLOT * SLOT_STRIDE),
                                 NB * HH * 2 / 16);

  // layer-0 gi GEMM (xn @ w0^T)
  gemm_tile<<<dim3(RT / 128, NCOL / 128), 256, 0, stream>>>(xn_bf, w0_bf, b_ih0, gi_bf, KP0);

  for (int lyr = 0; lyr < 3; ++lyr){
    zero16<<<1, 32, 0, stream>>>((uint4*)flags, 512 / 16);

    const unsigned short* whh_l = whh_bf + (size_t)lyr * 2 * G3 * HH;
    const float* bhh_l = (lyr == 0) ? b_hh0 : (b_hh + (size_t)(lyr - 1) * NCOL);
    unsigned short* outb = (lyr == 1) ? out1 : out0;
    int wout = (lyr < 2) ? 1 : 0;
    int do_next = (lyr < 2) ? 1 : 0;
    const unsigned short* wih_next = wih_bf + (size_t)lyr * NCOL * (2 * HH);  // valid lyr<2
    const float* bih_next = b_ih + (size_t)lyr * NCOL;
    fused_layer<<<256, 1024, 0, stream>>>(whh_l, bhh_l, gi_bf, outb,
                                          hfinal, hbig, flags, wout,
                                          (lyr < 2) ? wih_next : wih_bf,
                                          (lyr < 2) ? bih_next : fc_b,
                                          do_next);
  }
  fc_kernel<<<NB * NC, 64, 0, stream>>>(hfinal, fc_w, fc_b, out);
}

// Round 15
// 5786.429 us; speedup vs baseline: 2.7082x; 2.7082x over previous
//
#include <hip/hip_runtime.h>
#include <math.h>

// ---- problem constants ----
#define NB   64      // batch
#define TT   150     // timesteps
#define CIN  150
#define HH   1024
#define G3   3072    // 3*H
#define NCOL 6144    // 2*3072 (both directions)
#define KP0  160     // CIN padded to mult of 32
#define RT   9600    // T*N rows
#define NC   60
#define NSLOT 151            // h slots per direction (slot 0 = zeros)
#define SLOT_STRIDE 66560    // 64*1024 elems + 2048 elem (4KB) pad

using bf16x8 = __attribute__((ext_vector_type(8))) __bf16;
using f32x4  = __attribute__((ext_vector_type(4))) float;

static __device__ __forceinline__ unsigned short f2bf(float f){
  unsigned int x = __builtin_bit_cast(unsigned int, f);
  x += 0x7fffu + ((x >> 16) & 1u);          // RNE
  return (unsigned short)(x >> 16);
}
static __device__ __forceinline__ float bf2f(unsigned short u){
  unsigned int x = ((unsigned int)u) << 16;
  return __builtin_bit_cast(float, x);
}
static __device__ __forceinline__ float sigmoidf(float x){
  return 1.0f / (1.0f + expf(-x));
}

// async global->LDS, 16B per lane; LDS dest = wave-uniform base + lane*16
static __device__ __forceinline__ void gload16(const void* g, void* l){
  __builtin_amdgcn_global_load_lds(
      (const __attribute__((address_space(1))) void*)g,
      (__attribute__((address_space(3))) void*)l, 16, 0, 0);
}

// ---- BatchNorm stats: one block per channel ----
__global__ void bn_stats(const float* __restrict__ x, const float* __restrict__ gamma,
                         const float* __restrict__ beta, float* __restrict__ ss){
  const int c = blockIdx.x;
  float s = 0.f, s2 = 0.f;
  for (int i = threadIdx.x; i < RT; i += 256){
    float v = x[(size_t)i * CIN + c];
    s += v; s2 += v * v;
  }
  __shared__ float sh1[256], sh2[256];
  sh1[threadIdx.x] = s; sh2[threadIdx.x] = s2;
  __syncthreads();
  for (int st = 128; st > 0; st >>= 1){
    if ((int)threadIdx.x < st){
      sh1[threadIdx.x] += sh1[threadIdx.x + st];
      sh2[threadIdx.x] += sh2[threadIdx.x + st];
    }
    __syncthreads();
  }
  if (threadIdx.x == 0){
    float mean = sh1[0] * (1.f / RT);
    float var  = sh2[0] * (1.f / RT) - mean * mean;
    float sc   = rsqrtf(var + 1e-5f) * gamma[c];
    ss[c]       = sc;
    ss[CIN + c] = beta[c] - mean * sc;
  }
}

// ---- normalize + transpose [N,T,C] -> bf16 [t*64+n, KP0] with zero pad ----
__global__ void bn_apply(const float* __restrict__ x, const float* __restrict__ ss,
                         unsigned short* __restrict__ xn){
  int idx = blockIdx.x * 256 + threadIdx.x;
  if (idx >= RT * KP0) return;
  int r = idx / KP0, c = idx - r * KP0;
  int t = r >> 6, n = r & 63;
  float v = 0.f;
  if (c < CIN) v = x[((size_t)n * TT + t) * CIN + c] * ss[c] + ss[CIN + c];
  xn[idx] = f2bf(v);
}

// ---- cast fp32 -> bf16 (grid stride) ----
__global__ void cast_bf(const float* __restrict__ s, unsigned short* __restrict__ d, int n){
  for (int i = blockIdx.x * 256 + threadIdx.x; i < n; i += gridDim.x * 256)
    d[i] = f2bf(s[i]);
}

// ---- cast + pad w_ih0 [6144,150] -> [6144,160] bf16 ----
__global__ void cast_pad_w0(const float* __restrict__ w, unsigned short* __restrict__ d){
  int idx = blockIdx.x * 256 + threadIdx.x;
  if (idx >= NCOL * KP0) return;
  int row = idx / KP0, c = idx - row * KP0;
  d[idx] = (c < CIN) ? f2bf(w[(size_t)row * CIN + c]) : (unsigned short)0;
}

__global__ void zero16(uint4* p, int n){
  int i = blockIdx.x * 256 + threadIdx.x;
  if (i < n) p[i] = make_uint4(0u, 0u, 0u, 0u);
}

__global__ void guard_k(float* out){ out[0] = -12345.0f; }

// ---- tiled gi GEMM (m97 structure): C[r,col] = sum_k A[r,k]*B[col,k] + bias[col]
__global__ __launch_bounds__(256) void gemm_tile(
    const unsigned short* __restrict__ A, const unsigned short* __restrict__ B,
    const float* __restrict__ bias, unsigned short* __restrict__ C, int K)
{
  const int r0 = blockIdx.x * 128;
  const int c0 = blockIdx.y * 128;
  const int tid = threadIdx.x;
  const int wid = tid >> 6;
  const int l   = tid & 63;
  const int lr  = l & 15;
  const int lk  = (l >> 4) * 8;
  const int wm  = wid >> 1;       // wave row quadrant
  const int wn  = wid & 1;        // wave col quadrant

  __shared__ unsigned short As[128 * 32];
  __shared__ unsigned short Bs[128 * 32];

  const int c1   = wid * 64 + l;      // 16B-chunk id 0..255
  const int rowS = c1 >> 2;           // 0..63
  const int ccS  = c1 & 3;            // 16B chunk within row

  f32x4 acc[4][4];
#pragma unroll
  for (int i = 0; i < 4; ++i)
#pragma unroll
    for (int j = 0; j < 4; ++j) acc[i][j] = f32x4{0,0,0,0};

  const unsigned short* Ag0 = A + (size_t)(r0 + rowS) * K + ccS * 8;
  const unsigned short* Ag1 = A + (size_t)(r0 + 64 + rowS) * K + ccS * 8;
  const unsigned short* Bg0 = B + (size_t)(c0 + rowS) * K + ccS * 8;
  const unsigned short* Bg1 = B + (size_t)(c0 + 64 + rowS) * K + ccS * 8;
  unsigned short* As0 = As + wid * 512;
  unsigned short* As1 = As + 2048 + wid * 512;
  unsigned short* Bs0 = Bs + wid * 512;
  unsigned short* Bs1 = Bs + 2048 + wid * 512;

  for (int k0 = 0; k0 < K; k0 += 32){
    gload16(Ag0 + k0, As0);
    gload16(Ag1 + k0, As1);
    gload16(Bg0 + k0, Bs0);
    gload16(Bg1 + k0, Bs1);
    __syncthreads();

    bf16x8 af[4], bfr[4];
#pragma unroll
    for (int mt = 0; mt < 4; ++mt)
      af[mt] = *(const bf16x8*)(As + (wm * 64 + mt * 16 + lr) * 32 + lk);
#pragma unroll
    for (int nt = 0; nt < 4; ++nt)
      bfr[nt] = *(const bf16x8*)(Bs + (wn * 64 + nt * 16 + lr) * 32 + lk);
#pragma unroll
    for (int mt = 0; mt < 4; ++mt)
#pragma unroll
      for (int nt = 0; nt < 4; ++nt)
        acc[mt][nt] = __builtin_amdgcn_mfma_f32_16x16x32_bf16(af[mt], bfr[nt], acc[mt][nt], 0, 0, 0);
    __syncthreads();
  }

  const int rb = (l >> 4) * 4;
#pragma unroll
  for (int mt = 0; mt < 4; ++mt){
#pragma unroll
    for (int nt = 0; nt < 4; ++nt){
      const int col = c0 + wn * 64 + nt * 16 + lr;
      const float bv = bias[col];
#pragma unroll
      for (int reg = 0; reg < 4; ++reg){
        const int row = r0 + wm * 64 + mt * 16 + rb + reg;
        C[(size_t)row * NCOL + col] = f2bf(acc[mt][nt][reg] + bv);
      }
    }
  }
}

// ================= persistent GRU layer (r13 + per-quarter sub-counters) ======
// grid 128 = 2 dirs x 64 col-tiles, block 1024 (16 waves: wq=w&3 row-quad,
// kq=w>>2 k-quarter). Weights in LDS (96KB, slot-rotation). Write-once h slots.
// Sub-counters: h cols [q*256,(q+1)*256) come from producer blocks jt=q*16..+15
// -> 4 counters/dir. Producer block bumps counter jt>>4 once per step (release,
// after drain barrier). Consumer WAVE kq lane0-spins only on counter kq
// (fan-in 16, wave-converged, no block barrier) then loads immediately --
// quarter skew overlaps other quarters' compute.
__global__ __launch_bounds__(1024, 1) void gru_layer(
    const unsigned short* __restrict__ whh,   // [2][3072][1024] bf16
    const float* __restrict__ bhh,            // [2][3072]
    const unsigned short* __restrict__ gi,    // [9600][6144] bf16
    unsigned short* __restrict__ outb,        // [9600][2048] bf16 (may be unused)
    float* __restrict__ hfinal,               // [2][64][1024] f32 (t=149)
    unsigned short* __restrict__ hbig,        // [2][NSLOT][SLOT_STRIDE] bf16
    int* __restrict__ flags, int wout)
{
  const int d  = blockIdx.x >> 6;
  const int jt = blockIdx.x & 63;
  const int j0 = jt * 16;
  const int tid = threadIdx.x;
  const int w  = tid >> 6;        // 0..15
  const int wq = w & 3;           // row quad (16 batch rows)
  const int kq = w >> 2;          // k quarter: k in [kq*256, kq*256+256)
  const int l  = tid & 63;
  const int lr = l & 15;
  const int hi = l >> 4;

  __shared__ unsigned char wlds[98304];   // 3 planes of 32KB: [16 rows][2048B]
  __shared__ f32x4 red4[2304];            // [12 src waves][3 gates][64 lanes], 36KB

  // ---- load weight slice to LDS (once). Slot-rotation layout. ----
  {
    const unsigned short* wsrc = whh + (size_t)d * (G3 * HH);
    for (int c = tid; c < 6144; c += 1024){    // 16B chunks
      int g   = c >> 11;
      int rem = c & 2047;
      int r   = rem >> 7;
      int kc  = rem & 127;
      uint4 v = *(const uint4*)(wsrc + (size_t)(g * HH + j0 + r) * HH + kc * 8);
      int kcs = (kc & ~7) | ((kc + r) & 7);
      *(uint4*)(wlds + g * 32768 + r * 2048 + kcs * 16) = v;
    }
  }
  __syncthreads();

  // biases for epilogue waves (kq==0): gc = j0 + hi*4 + reg
  float4 br4 = make_float4(0, 0, 0, 0), bz4 = br4, bn4 = br4;
  if (kq == 0){
    br4 = *(const float4*)(bhh + d * G3 +          j0 + hi * 4);
    bz4 = *(const float4*)(bhh + d * G3 + HH +     j0 + hi * 4);
    bn4 = *(const float4*)(bhh + d * G3 + 2 * HH + j0 + hi * 4);
  }

  const int n    = wq * 16 + lr;           // batch row this lane handles
  const int jcol = j0 + hi * 4;            // first of 4 hidden cols (epilogue)

  unsigned short* dirbase = hbig + (size_t)d * NSLOT * SLOT_STRIDE;
  int* myctr   = &flags[d * 256 + kq * 64];         // quarter this WAVE consumes
  int* bumpctr = &flags[d * 256 + (jt >> 4) * 64];  // quarter this BLOCK produces

  float hold[4] = {0.f, 0.f, 0.f, 0.f};    // fp32 master h for (n, jcol..+3)

  for (int t = 0; t < TT; ++t){
    const unsigned short* hprev = dirbase + (size_t)t * SLOT_STRIDE;
    unsigned short*       hnext = dirbase + (size_t)(t + 1) * SLOT_STRIDE;

    // ---- gi prefetch (epilogue waves only) BEFORE the poll ----
    ushort4 gr4, gz4, gn4;
    if (kq == 0){
      size_t gbase = (size_t)(t * NB + n) * NCOL + (size_t)d * G3 + jcol;
      gr4 = *(const ushort4*)(gi + gbase);
      gz4 = *(const ushort4*)(gi + gbase + HH);
      gn4 = *(const ushort4*)(gi + gbase + 2 * HH);
    }

    // ---- per-WAVE quarter wait (16 producers, no block barrier) ----
    if (t){
      if (l == 0){
        const int tgt = 16 * t;
        int cap = 0;
        while (__hip_atomic_load(myctr, __ATOMIC_RELAXED, __HIP_MEMORY_SCOPE_AGENT) < tgt){
          if (++cap > 20000000) break;
          __builtin_amdgcn_s_sleep(1);
        }
      }
      // wave reconverges here: all 64 lanes waited on lane 0's spin
    }

    f32x4 ar = {0,0,0,0}, az = {0,0,0,0}, an = {0,0,0,0};
    // this wave's h: rows n, k in [kq*256, kq*256+256); lane covers +hi*8
    const unsigned short* hrow = hprev + (size_t)n * HH + kq * 256 + hi * 8;

    bf16x8 ha[8];
#pragma unroll
    for (int i = 0; i < 8; ++i) ha[i] = *(const bf16x8*)(hrow + i * 32);

#pragma unroll
    for (int i = 0; i < 8; ++i){
      const int kc  = kq * 32 + i * 4 + hi;      // 16B chunk index in row
      const int kcs = (kc & ~7) | ((kc + lr) & 7);
      const int off = lr * 2048 + kcs * 16;
      bf16x8 a_r = *(const bf16x8*)(wlds +          off);
      bf16x8 a_z = *(const bf16x8*)(wlds + 32768 +  off);
      bf16x8 a_n = *(const bf16x8*)(wlds + 65536 +  off);
      ar = __builtin_amdgcn_mfma_f32_16x16x32_bf16(a_r, ha[i], ar, 0, 0, 0);
      az = __builtin_amdgcn_mfma_f32_16x16x32_bf16(a_z, ha[i], az, 0, 0, 0);
      an = __builtin_amdgcn_mfma_f32_16x16x32_bf16(a_n, ha[i], an, 0, 0, 0);
    }

    // ---- k-split reduce: kq 1..3 write partials, kq 0 accumulates ----
    __syncthreads();
    if (kq > 0){
      const int src = (kq - 1) * 4 + wq;        // 0..11
      red4[(src * 3 + 0) * 64 + l] = ar;
      red4[(src * 3 + 1) * 64 + l] = az;
      red4[(src * 3 + 2) * 64 + l] = an;
    }
    __syncthreads();

    if (kq == 0){
#pragma unroll
      for (int kqp = 1; kqp < 4; ++kqp){
        const int src = (kqp - 1) * 4 + wq;
        ar += red4[(src * 3 + 0) * 64 + l];
        az += red4[(src * 3 + 1) * 64 + l];
        an += red4[(src * 3 + 2) * 64 + l];
      }

      // ---- epilogue: gates + h update for (n, jcol..jcol+3) ----
      ushort4 hb_;
      const float* br = (const float*)&br4;
      const float* bz = (const float*)&bz4;
      const float* bn_ = (const float*)&bn4;
      const unsigned short* g_r = (const unsigned short*)&gr4;
      const unsigned short* g_z = (const unsigned short*)&gz4;
      const unsigned short* g_n = (const unsigned short*)&gn4;
#pragma unroll
      for (int reg = 0; reg < 4; ++reg){
        float r  = sigmoidf(bf2f(g_r[reg]) + ar[reg] + br[reg]);
        float z  = sigmoidf(bf2f(g_z[reg]) + az[reg] + bz[reg]);
        float nn = tanhf(bf2f(g_n[reg]) + r * (an[reg] + bn_[reg]));
        hold[reg] = (1.f - z) * nn + z * hold[reg];
      }
      hb_.x = f2bf(hold[0]); hb_.y = f2bf(hold[1]);
      hb_.z = f2bf(hold[2]); hb_.w = f2bf(hold[3]);
      // write-through to coherence point FIRST (longest latency to drain):
      __hip_atomic_store((unsigned long long*)(hnext + (size_t)n * HH + jcol),
                         __builtin_bit_cast(unsigned long long, hb_),
                         __ATOMIC_RELAXED, __HIP_MEMORY_SCOPE_AGENT);
      if (wout)
        *(ushort4*)(outb + (size_t)(t * NB + n) * (2 * HH) + (size_t)d * HH + jcol) = hb_;
      if (t == TT - 1)
        *(float4*)(hfinal + (size_t)(d * NB + n) * HH + jcol) =
            make_float4(hold[0], hold[1], hold[2], hold[3]);
    }

    // ---- publish: barrier drains all waves' stores, then bump own quarter ----
    __syncthreads();
    if (tid == 0)
      __hip_atomic_fetch_add(bumpctr, 1, __ATOMIC_RELEASE, __HIP_MEMORY_SCOPE_AGENT);
  }
}

// ---- final FC ----
__global__ void fc_kernel(const float* __restrict__ hf, const float* __restrict__ fw,
                          const float* __restrict__ fb, float* __restrict__ out){
  int b = blockIdx.x;
  int n = b / NC, c = b - n * NC;
  int l = threadIdx.x;
  float s = 0.f;
  for (int k = l; k < 2 * HH; k += 64){
    float hv = (k < HH) ? hf[(size_t)n * HH + k]
                        : hf[(size_t)(NB + n) * HH + (k - HH)];
    s += hv * fw[(size_t)c * (2 * HH) + k];
  }
#pragma unroll
  for (int off = 32; off > 0; off >>= 1) s += __shfl_down(s, off);
  if (l == 0) out[n * NC + c] = s + fb[c];
}

extern "C" void kernel_launch(void* const* d_in, const int* in_sizes, int n_in,
                              void* d_out, int out_size, void* d_ws, size_t ws_size,
                              hipStream_t stream)
{
  const float* x      = (const float*)d_in[0];
  const float* gamma  = (const float*)d_in[1];
  const float* beta   = (const float*)d_in[2];
  const float* w_ih0  = (const float*)d_in[3];
  const float* w_hh0  = (const float*)d_in[4];
  const float* b_ih0  = (const float*)d_in[5];
  const float* b_hh0  = (const float*)d_in[6];
  const float* w_ih   = (const float*)d_in[7];
  const float* w_hh   = (const float*)d_in[8];
  const float* b_ih   = (const float*)d_in[9];
  const float* b_hh   = (const float*)d_in[10];
  const float* fc_w   = (const float*)d_in[11];
  const float* fc_b   = (const float*)d_in[12];
  float* out = (float*)d_out;

  char* ws = (char*)d_ws;
  size_t off = 0;
  auto alloc = [&](size_t bytes)->void*{
    void* p = ws + off; off += (bytes + 255) & ~(size_t)255; return p;
  };
  unsigned short* whh_bf = (unsigned short*)alloc((size_t)3 * 2 * G3 * HH * 2);
  unsigned short* w0_bf  = (unsigned short*)alloc((size_t)NCOL * KP0 * 2);
  unsigned short* wih_bf = (unsigned short*)alloc((size_t)2 * NCOL * 2 * HH * 2);
  unsigned short* xn_bf  = (unsigned short*)alloc((size_t)RT * KP0 * 2);
  unsigned short* gi_bf  = (unsigned short*)alloc((size_t)RT * NCOL * 2);
  unsigned short* out0   = (unsigned short*)alloc((size_t)RT * 2 * HH * 2);
  unsigned short* out1   = (unsigned short*)alloc((size_t)RT * 2 * HH * 2);
  float* hfinal = (float*)alloc((size_t)2 * NB * HH * 4);
  unsigned short* hbig = (unsigned short*)alloc((size_t)2 * NSLOT * SLOT_STRIDE * 2);
  float* ss = (float*)alloc(2048);
  int* flags = (int*)alloc(2048);

  if (off > ws_size){ guard_k<<<1, 1, 0, stream>>>(out); return; }

  // BN + casts
  bn_stats<<<CIN, 256, 0, stream>>>(x, gamma, beta, ss);
  bn_apply<<<(RT * KP0 + 255) / 256, 256, 0, stream>>>(x, ss, xn_bf);
  cast_pad_w0<<<(NCOL * KP0 + 255) / 256, 256, 0, stream>>>(w_ih0, w0_bf);
  cast_bf<<<4096, 256, 0, stream>>>(w_hh0, whh_bf, 2 * G3 * HH);
  cast_bf<<<4096, 256, 0, stream>>>(w_hh,  whh_bf + (size_t)2 * G3 * HH, 2 * 2 * G3 * HH);
  cast_bf<<<4096, 256, 0, stream>>>(w_ih,  wih_bf, 2 * NCOL * 2 * HH);

  // zero slot 0 of both directions (h^0 = 0) — every call (ws is poisoned)
  zero16<<<32, 256, 0, stream>>>((uint4*)hbig, NB * HH * 2 / 16);
  zero16<<<32, 256, 0, stream>>>((uint4*)(hbig + (size_t)NSLOT * SLOT_STRIDE),
                                 NB * HH * 2 / 16);

  for (int lyr = 0; lyr < 3; ++lyr){
    if (lyr == 0){
      gemm_tile<<<dim3(RT / 128, NCOL / 128), 256, 0, stream>>>(xn_bf, w0_bf, b_ih0, gi_bf, KP0);
    } else {
      const unsigned short* Ain = (lyr == 1) ? out0 : out1;
      gemm_tile<<<dim3(RT / 128, NCOL / 128), 256, 0, stream>>>(
          Ain, wih_bf + (size_t)(lyr - 1) * NCOL * 2 * HH,
          b_ih + (size_t)(lyr - 1) * NCOL, gi_bf, 2 * HH);
    }
    zero16<<<1, 128, 0, stream>>>((uint4*)flags, 2048 / 16);

    const unsigned short* whh_l = whh_bf + (size_t)lyr * 2 * G3 * HH;
    const float* bhh_l = (lyr == 0) ? b_hh0 : (b_hh + (size_t)(lyr - 1) * NCOL);
    unsigned short* outb = (lyr == 0) ? out0 : out1;
    int wout = (lyr < 2) ? 1 : 0;
    gru_layer<<<128, 1024, 0, stream>>>(whh_l, bhh_l, gi_bf, outb,
                                        hfinal, hbig, flags, wout);
  }
  fc_kernel<<<NB * NC, 64, 0, stream>>>(hfinal, fc_w, fc_b, out);
}

// Round 16
// 5441.983 us; speedup vs baseline: 2.8796x; 1.0633x over previous
//
#include <hip/hip_runtime.h>
#include <math.h>

// ---- problem constants ----
#define NB   64      // batch
#define TT   150     // timesteps
#define CIN  150
#define HH   1024
#define G3   3072    // 3*H
#define NCOL 6144    // 2*3072 (both directions)
#define KP0  160     // CIN padded to mult of 32
#define RT   9600    // T*N rows
#define NC   60
#define NSLOT 151            // h slots per direction (slot 0 = zeros)
#define SLOT_STRIDE 66560    // 64*1024 elems + 2048 elem (4KB) pad

using bf16x8 = __attribute__((ext_vector_type(8))) __bf16;
using f32x4  = __attribute__((ext_vector_type(4))) float;

static __device__ __forceinline__ unsigned short f2bf(float f){
  unsigned int x = __builtin_bit_cast(unsigned int, f);
  x += 0x7fffu + ((x >> 16) & 1u);          // RNE
  return (unsigned short)(x >> 16);
}
static __device__ __forceinline__ float bf2f(unsigned short u){
  unsigned int x = ((unsigned int)u) << 16;
  return __builtin_bit_cast(float, x);
}
static __device__ __forceinline__ float sigmoidf(float x){
  return 1.0f / (1.0f + expf(-x));
}

// async global->LDS, 16B per lane; LDS dest = wave-uniform base + lane*16
static __device__ __forceinline__ void gload16(const void* g, void* l){
  __builtin_amdgcn_global_load_lds(
      (const __attribute__((address_space(1))) void*)g,
      (__attribute__((address_space(3))) void*)l, 16, 0, 0);
}

// ---- BatchNorm stats: one block per channel ----
__global__ void bn_stats(const float* __restrict__ x, const float* __restrict__ gamma,
                         const float* __restrict__ beta, float* __restrict__ ss){
  const int c = blockIdx.x;
  float s = 0.f, s2 = 0.f;
  for (int i = threadIdx.x; i < RT; i += 256){
    float v = x[(size_t)i * CIN + c];
    s += v; s2 += v * v;
  }
  __shared__ float sh1[256], sh2[256];
  sh1[threadIdx.x] = s; sh2[threadIdx.x] = s2;
  __syncthreads();
  for (int st = 128; st > 0; st >>= 1){
    if ((int)threadIdx.x < st){
      sh1[threadIdx.x] += sh1[threadIdx.x + st];
      sh2[threadIdx.x] += sh2[threadIdx.x + st];
    }
    __syncthreads();
  }
  if (threadIdx.x == 0){
    float mean = sh1[0] * (1.f / RT);
    float var  = sh2[0] * (1.f / RT) - mean * mean;
    float sc   = rsqrtf(var + 1e-5f) * gamma[c];
    ss[c]       = sc;
    ss[CIN + c] = beta[c] - mean * sc;
  }
}

// ---- normalize + transpose [N,T,C] -> bf16 [t*64+n, KP0] with zero pad ----
__global__ void bn_apply(const float* __restrict__ x, const float* __restrict__ ss,
                         unsigned short* __restrict__ xn){
  int idx = blockIdx.x * 256 + threadIdx.x;
  if (idx >= RT * KP0) return;
  int r = idx / KP0, c = idx - r * KP0;
  int t = r >> 6, n = r & 63;
  float v = 0.f;
  if (c < CIN) v = x[((size_t)n * TT + t) * CIN + c] * ss[c] + ss[CIN + c];
  xn[idx] = f2bf(v);
}

// ---- cast fp32 -> bf16 (grid stride) ----
__global__ void cast_bf(const float* __restrict__ s, unsigned short* __restrict__ d, int n){
  for (int i = blockIdx.x * 256 + threadIdx.x; i < n; i += gridDim.x * 256)
    d[i] = f2bf(s[i]);
}

// ---- cast + pad w_ih0 [6144,150] -> [6144,160] bf16 ----
__global__ void cast_pad_w0(const float* __restrict__ w, unsigned short* __restrict__ d){
  int idx = blockIdx.x * 256 + threadIdx.x;
  if (idx >= NCOL * KP0) return;
  int row = idx / KP0, c = idx - row * KP0;
  d[idx] = (c < CIN) ? f2bf(w[(size_t)row * CIN + c]) : (unsigned short)0;
}

__global__ void zero16(uint4* p, int n){
  int i = blockIdx.x * 256 + threadIdx.x;
  if (i < n) p[i] = make_uint4(0u, 0u, 0u, 0u);
}

__global__ void guard_k(float* out){ out[0] = -12345.0f; }

// ---- tiled gi GEMM (m97 structure): C[r,col] = sum_k A[r,k]*B[col,k] + bias[col]
// 128x128 tile, BK=32, 4 waves (2x2 of 64x64), LDS 16KB via global_load_lds w16.
__global__ __launch_bounds__(256) void gemm_tile(
    const unsigned short* __restrict__ A, const unsigned short* __restrict__ B,
    const float* __restrict__ bias, unsigned short* __restrict__ C, int K)
{
  const int r0 = blockIdx.x * 128;
  const int c0 = blockIdx.y * 128;
  const int tid = threadIdx.x;
  const int wid = tid >> 6;
  const int l   = tid & 63;
  const int lr  = l & 15;
  const int lk  = (l >> 4) * 8;
  const int wm  = wid >> 1;       // wave row quadrant
  const int wn  = wid & 1;        // wave col quadrant

  __shared__ unsigned short As[128 * 32];
  __shared__ unsigned short Bs[128 * 32];

  const int c1   = wid * 64 + l;      // 16B-chunk id 0..255 (this thread's chunk)
  const int rowS = c1 >> 2;           // 0..63
  const int ccS  = c1 & 3;            // 16B chunk within row

  f32x4 acc[4][4];
#pragma unroll
  for (int i = 0; i < 4; ++i)
#pragma unroll
    for (int j = 0; j < 4; ++j) acc[i][j] = f32x4{0,0,0,0};

  const unsigned short* Ag0 = A + (size_t)(r0 + rowS) * K + ccS * 8;
  const unsigned short* Ag1 = A + (size_t)(r0 + 64 + rowS) * K + ccS * 8;
  const unsigned short* Bg0 = B + (size_t)(c0 + rowS) * K + ccS * 8;
  const unsigned short* Bg1 = B + (size_t)(c0 + 64 + rowS) * K + ccS * 8;
  unsigned short* As0 = As + wid * 512;          // issue0 wave base (bytes: wid*1024)
  unsigned short* As1 = As + 2048 + wid * 512;   // issue1 (rows 64..127)
  unsigned short* Bs0 = Bs + wid * 512;
  unsigned short* Bs1 = Bs + 2048 + wid * 512;

  for (int k0 = 0; k0 < K; k0 += 32){
    gload16(Ag0 + k0, As0);
    gload16(Ag1 + k0, As1);
    gload16(Bg0 + k0, Bs0);
    gload16(Bg1 + k0, Bs1);
    __syncthreads();                 // drains vmcnt -> tiles resident

    bf16x8 af[4], bfr[4];
#pragma unroll
    for (int mt = 0; mt < 4; ++mt)
      af[mt] = *(const bf16x8*)(As + (wm * 64 + mt * 16 + lr) * 32 + lk);
#pragma unroll
    for (int nt = 0; nt < 4; ++nt)
      bfr[nt] = *(const bf16x8*)(Bs + (wn * 64 + nt * 16 + lr) * 32 + lk);
#pragma unroll
    for (int mt = 0; mt < 4; ++mt)
#pragma unroll
      for (int nt = 0; nt < 4; ++nt)
        acc[mt][nt] = __builtin_amdgcn_mfma_f32_16x16x32_bf16(af[mt], bfr[nt], acc[mt][nt], 0, 0, 0);
    __syncthreads();                 // LDS free for next stage
  }

  const int rb = (l >> 4) * 4;
#pragma unroll
  for (int mt = 0; mt < 4; ++mt){
#pragma unroll
    for (int nt = 0; nt < 4; ++nt){
      const int col = c0 + wn * 64 + nt * 16 + lr;
      const float bv = bias[col];
#pragma unroll
      for (int reg = 0; reg < 4; ++reg){
        const int row = r0 + wm * 64 + mt * 16 + rb + reg;
        C[(size_t)row * NCOL + col] = f2bf(acc[mt][nt][reg] + bv);
      }
    }
  }
}

// ================= persistent GRU layer =================
// grid 128 = 2 dirs x 64 col-tiles (16 hidden cols each), block 512 (8 waves,
// 2 waves/SIMD for latency hiding). Wave pair (w, w+4) shares batch rows
// [wq*16, wq*16+16) and splits k: [0,512) / [512,1024); partials reduced in LDS.
// Weights (3 gates x 16 cols x 1024) in LDS (96KB, slot-rotation layout).
// h exchange: WRITE-ONCE slot per timestep; single counter barrier per dir.
__global__ __launch_bounds__(512, 1) void gru_layer(
    const unsigned short* __restrict__ whh,   // [2][3072][1024] bf16
    const float* __restrict__ bhh,            // [2][3072]
    const unsigned short* __restrict__ gi,    // [9600][6144] bf16
    unsigned short* __restrict__ outb,        // [9600][2048] bf16 (may be unused)
    float* __restrict__ hfinal,               // [2][64][1024] f32 (written at t=149)
    unsigned short* __restrict__ hbig,        // [2][NSLOT][SLOT_STRIDE] bf16
    int* __restrict__ flags, int wout)
{
  const int d  = blockIdx.x >> 6;
  const int jt = blockIdx.x & 63;
  const int j0 = jt * 16;
  const int tid = threadIdx.x;
  const int w  = tid >> 6;        // 0..7
  const int wq = w & 3;           // row quad (shared by wave pair)
  const int kh = w >> 2;          // k half: 0 -> [0,512), 1 -> [512,1024)
  const int l  = tid & 63;
  const int lr = l & 15;
  const int hi = l >> 4;

  __shared__ unsigned char wlds[98304];   // 3 planes of 32KB: [16 rows][2048B]
  __shared__ f32x4 red[3][256];           // k-split partial sums (12 KB)

  // ---- load weight slice to LDS (once). Slot-rotation layout:
  // 16B-chunk kc within a row r stored at kc' = (kc & ~7) | ((kc + r) & 7).
  {
    const unsigned short* wsrc = whh + (size_t)d * (G3 * HH);
    for (int c = tid; c < 6144; c += 512){     // 16B chunks
      int g   = c >> 11;
      int rem = c & 2047;
      int r   = rem >> 7;
      int kc  = rem & 127;
      uint4 v = *(const uint4*)(wsrc + (size_t)(g * HH + j0 + r) * HH + kc * 8);
      int kcs = (kc & ~7) | ((kc + r) & 7);
      *(uint4*)(wlds + g * 32768 + r * 2048 + kcs * 16) = v;
    }
  }
  __syncthreads();

  // biases for epilogue lanes (waves 0-3 only): gc = j0 + hi*4 + reg
  float4 br4 = make_float4(0, 0, 0, 0), bz4 = br4, bn4 = br4;
  if (w < 4){
    br4 = *(const float4*)(bhh + d * G3 +          j0 + hi * 4);
    bz4 = *(const float4*)(bhh + d * G3 + HH +     j0 + hi * 4);
    bn4 = *(const float4*)(bhh + d * G3 + 2 * HH + j0 + hi * 4);
  }

  const int n    = wq * 16 + lr;           // batch row this lane handles
  const int jcol = j0 + hi * 4;            // first of 4 hidden cols (epilogue)

  unsigned short* dirbase = hbig + (size_t)d * NSLOT * SLOT_STRIDE;
  int* ctr = &flags[d * 64];               // 256B-separated counter per direction

  float hold[4] = {0.f, 0.f, 0.f, 0.f};    // fp32 master h for (n, jcol..+3)

  for (int t = 0; t < TT; ++t){
    const unsigned short* hprev = dirbase + (size_t)t * SLOT_STRIDE;
    unsigned short*       hnext = dirbase + (size_t)(t + 1) * SLOT_STRIDE;

    // ---- gi prefetch (epilogue waves only) BEFORE the poll ----
    ushort4 gr4, gz4, gn4;
    if (w < 4){
      size_t gbase = (size_t)(t * NB + n) * NCOL + (size_t)d * G3 + jcol;
      gr4 = *(const ushort4*)(gi + gbase);
      gz4 = *(const ushort4*)(gi + gbase + HH);
      gn4 = *(const ushort4*)(gi + gbase + 2 * HH);
    }

    // ---- wait for all 64 producers of h^t: single counter, single poller ----
    if (t){
      if (tid == 0){
        const int tgt = 64 * t;
        int cap = 0;
        while (__hip_atomic_load(ctr, __ATOMIC_RELAXED, __HIP_MEMORY_SCOPE_AGENT) < tgt){
          if (++cap > 20000000) break;
          __builtin_amdgcn_s_sleep(1);
        }
      }
      __syncthreads();
    }

    f32x4 ar = {0,0,0,0}, az = {0,0,0,0}, an = {0,0,0,0};
    // this wave's h: rows n, k in [kh*512, kh*512+512); lane covers +hi*8
    const unsigned short* hrow = hprev + (size_t)n * HH + kh * 512 + hi * 8;

    bf16x8 ha[8], hb2[8];
#pragma unroll
    for (int i = 0; i < 8; ++i) ha[i] = *(const bf16x8*)(hrow + i * 32);

#pragma unroll
    for (int half = 0; half < 2; ++half){
      if (half == 0){
#pragma unroll
        for (int i = 0; i < 8; ++i)
          hb2[i] = *(const bf16x8*)(hrow + 256 + i * 32);
      }
#pragma unroll
      for (int i = 0; i < 8; ++i){
        const int it  = half * 8 + i;              // 0..15
        const int kc  = kh * 64 + it * 4 + hi;     // 16B chunk index in row
        const int kcs = (kc & ~7) | ((kc + lr) & 7);
        const int off = lr * 2048 + kcs * 16;
        bf16x8 a_r = *(const bf16x8*)(wlds +          off);
        bf16x8 a_z = *(const bf16x8*)(wlds + 32768 +  off);
        bf16x8 a_n = *(const bf16x8*)(wlds + 65536 +  off);
        ar = __builtin_amdgcn_mfma_f32_16x16x32_bf16(a_r, ha[i], ar, 0, 0, 0);
        az = __builtin_amdgcn_mfma_f32_16x16x32_bf16(a_z, ha[i], az, 0, 0, 0);
        an = __builtin_amdgcn_mfma_f32_16x16x32_bf16(a_n, ha[i], an, 0, 0, 0);
      }
      if (half == 0){
#pragma unroll
        for (int i = 0; i < 8; ++i) ha[i] = hb2[i];
      }
    }

    // ---- k-split reduce: waves 4-7 hand partials to waves 0-3 ----
    __syncthreads();
    if (w >= 4){
      red[0][wq * 64 + l] = ar;
      red[1][wq * 64 + l] = az;
      red[2][wq * 64 + l] = an;
    }
    __syncthreads();

    if (w < 4){
      ar += red[0][wq * 64 + l];
      az += red[1][wq * 64 + l];
      an += red[2][wq * 64 + l];

      // ---- epilogue: gates + h update for (n, jcol..jcol+3) ----
      ushort4 hb_;
      const float* br = (const float*)&br4;
      const float* bz = (const float*)&bz4;
      const float* bn_ = (const float*)&bn4;
      const unsigned short* g_r = (const unsigned short*)&gr4;
      const unsigned short* g_z = (const unsigned short*)&gz4;
      const unsigned short* g_n = (const unsigned short*)&gn4;
#pragma unroll
      for (int reg = 0; reg < 4; ++reg){
        float r  = sigmoidf(bf2f(g_r[reg]) + ar[reg] + br[reg]);
        float z  = sigmoidf(bf2f(g_z[reg]) + az[reg] + bz[reg]);
        float nn = tanhf(bf2f(g_n[reg]) + r * (an[reg] + bn_[reg]));
        hold[reg] = (1.f - z) * nn + z * hold[reg];
      }
      hb_.x = f2bf(hold[0]); hb_.y = f2bf(hold[1]);
      hb_.z = f2bf(hold[2]); hb_.w = f2bf(hold[3]);
      // write-through to coherence point FIRST (longest latency to drain):
      __hip_atomic_store((unsigned long long*)(hnext + (size_t)n * HH + jcol),
                         __builtin_bit_cast(unsigned long long, hb_),
                         __ATOMIC_RELAXED, __HIP_MEMORY_SCOPE_AGENT);
      if (wout)
        *(ushort4*)(outb + (size_t)(t * NB + n) * (2 * HH) + (size_t)d * HH + jcol) = hb_;
      if (t == TT - 1)
        *(float4*)(hfinal + (size_t)(d * NB + n) * HH + jcol) =
            make_float4(hold[0], hold[1], hold[2], hold[3]);
    }

    // ---- publish: barrier drains all waves' stores, then bump counter ----
    __syncthreads();
    if (tid == 0)
      __hip_atomic_fetch_add(ctr, 1, __ATOMIC_RELEASE, __HIP_MEMORY_SCOPE_AGENT);
  }
}

// ---- final FC ----
__global__ void fc_kernel(const float* __restrict__ hf, const float* __restrict__ fw,
                          const float* __restrict__ fb, float* __restrict__ out){
  int b = blockIdx.x;
  int n = b / NC, c = b - n * NC;
  int l = threadIdx.x;
  float s = 0.f;
  for (int k = l; k < 2 * HH; k += 64){
    float hv = (k < HH) ? hf[(size_t)n * HH + k]
                        : hf[(size_t)(NB + n) * HH + (k - HH)];
    s += hv * fw[(size_t)c * (2 * HH) + k];
  }
#pragma unroll
  for (int off = 32; off > 0; off >>= 1) s += __shfl_down(s, off);
  if (l == 0) out[n * NC + c] = s + fb[c];
}

extern "C" void kernel_launch(void* const* d_in, const int* in_sizes, int n_in,
                              void* d_out, int out_size, void* d_ws, size_t ws_size,
                              hipStream_t stream)
{
  const float* x      = (const float*)d_in[0];
  const float* gamma  = (const float*)d_in[1];
  const float* beta   = (const float*)d_in[2];
  const float* w_ih0  = (const float*)d_in[3];
  const float* w_hh0  = (const float*)d_in[4];
  const float* b_ih0  = (const float*)d_in[5];
  const float* b_hh0  = (const float*)d_in[6];
  const float* w_ih   = (const float*)d_in[7];
  const float* w_hh   = (const float*)d_in[8];
  const float* b_ih   = (const float*)d_in[9];
  const float* b_hh   = (const float*)d_in[10];
  const float* fc_w   = (const float*)d_in[11];
  const float* fc_b   = (const float*)d_in[12];
  float* out = (float*)d_out;

  char* ws = (char*)d_ws;
  size_t off = 0;
  auto alloc = [&](size_t bytes)->void*{
    void* p = ws + off; off += (bytes + 255) & ~(size_t)255; return p;
  };
  unsigned short* whh_bf = (unsigned short*)alloc((size_t)3 * 2 * G3 * HH * 2);
  unsigned short* w0_bf  = (unsigned short*)alloc((size_t)NCOL * KP0 * 2);
  unsigned short* wih_bf = (unsigned short*)alloc((size_t)2 * NCOL * 2 * HH * 2);
  unsigned short* xn_bf  = (unsigned short*)alloc((size_t)RT * KP0 * 2);
  unsigned short* gi_bf  = (unsigned short*)alloc((size_t)RT * NCOL * 2);
  unsigned short* out0   = (unsigned short*)alloc((size_t)RT * 2 * HH * 2);
  unsigned short* out1   = (unsigned short*)alloc((size_t)RT * 2 * HH * 2);
  float* hfinal = (float*)alloc((size_t)2 * NB * HH * 4);
  unsigned short* hbig = (unsigned short*)alloc((size_t)2 * NSLOT * SLOT_STRIDE * 2);
  float* ss = (float*)alloc(2048);
  int* flags = (int*)alloc(1024);

  if (off > ws_size){ guard_k<<<1, 1, 0, stream>>>(out); return; }

  // BN + casts
  bn_stats<<<CIN, 256, 0, stream>>>(x, gamma, beta, ss);
  bn_apply<<<(RT * KP0 + 255) / 256, 256, 0, stream>>>(x, ss, xn_bf);
  cast_pad_w0<<<(NCOL * KP0 + 255) / 256, 256, 0, stream>>>(w_ih0, w0_bf);
  cast_bf<<<4096, 256, 0, stream>>>(w_hh0, whh_bf, 2 * G3 * HH);
  cast_bf<<<4096, 256, 0, stream>>>(w_hh,  whh_bf + (size_t)2 * G3 * HH, 2 * 2 * G3 * HH);
  cast_bf<<<4096, 256, 0, stream>>>(w_ih,  wih_bf, 2 * NCOL * 2 * HH);

  // zero slot 0 of both directions (h^0 = 0) — every call (ws is poisoned)
  zero16<<<32, 256, 0, stream>>>((uint4*)hbig, NB * HH * 2 / 16);
  zero16<<<32, 256, 0, stream>>>((uint4*)(hbig + (size_t)NSLOT * SLOT_STRIDE),
                                 NB * HH * 2 / 16);

  for (int lyr = 0; lyr < 3; ++lyr){
    if (lyr == 0){
      gemm_tile<<<dim3(RT / 128, NCOL / 128), 256, 0, stream>>>(xn_bf, w0_bf, b_ih0, gi_bf, KP0);
    } else {
      const unsigned short* Ain = (lyr == 1) ? out0 : out1;
      gemm_tile<<<dim3(RT / 128, NCOL / 128), 256, 0, stream>>>(
          Ain, wih_bf + (size_t)(lyr - 1) * NCOL * 2 * HH,
          b_ih + (size_t)(lyr - 1) * NCOL, gi_bf, 2 * HH);
    }
    zero16<<<1, 32, 0, stream>>>((uint4*)flags, 512 / 16);

    const unsigned short* whh_l = whh_bf + (size_t)lyr * 2 * G3 * HH;
    const float* bhh_l = (lyr == 0) ? b_hh0 : (b_hh + (size_t)(lyr - 1) * NCOL);
    unsigned short* outb = (lyr == 0) ? out0 : out1;
    int wout = (lyr < 2) ? 1 : 0;
    gru_layer<<<128, 512, 0, stream>>>(whh_l, bhh_l, gi_bf, outb,
                                       hfinal, hbig, flags, wout);
  }
  fc_kernel<<<NB * NC, 64, 0, stream>>>(hfinal, fc_w, fc_b, out);
}